// Round 7
// baseline (303.250 us; speedup 1.0000x reference)
//
#include <hip/hip_runtime.h>

#define H 768
#define W 768
#define SW 256        // output cols per strip
#define RW 272        // region width (SW + 16)
#define ABW 264       // A,b row width (SW + 8)
#define ROWS 32       // output rows per band
#define NSTEP 24      // (ROWS + 16) / 2 double-row steps
#define RADIUS 4

// All register rings use LITERAL indices + explicit shifts: immune to the
// failed-unroll -> runtime-index -> scratch demotion that killed R5/R6
// (VGPR=64 + 640MB scratch traffic despite the 128-VGPR launch_bounds cap).
__global__ __launch_bounds__(256, 4) void gf_stream5(
    const float* __restrict__ xg, const float* __restrict__ yg,
    float* __restrict__ outg)
{
    __shared__ float4 xybuf[2][RW];   // (x0,y0,x1,y1)   8704 B
    __shared__ float4 abbuf[2][ABW];  // (A0,B0,A1,B1)   8448 B
    __shared__ float4 tring[9][8];    // extra-col h-ring 1152 B  (18304 B)

    const int t     = threadIdx.x;
    const int base  = blockIdx.x * SW;
    const int R0    = blockIdx.y * ROWS;
    const int plane = blockIdx.z;

    const float* xp = xg + (size_t)plane * (H * W);
    const float* yp = yg + (size_t)plane * (H * W);
    float*       op = outg + (size_t)plane * (H * W);

    // ---- per-thread column geometry (loop-invariant) ----
    const int  a_abs   = base + t - 4;
    const bool a_colok = (a_abs >= 0) && (a_abs < W);
    const float invCwA = a_colok
        ? 1.0f / (float)(min(a_abs + RADIUS, W - 1) - max(a_abs - RADIUS, 0) + 1) : 0.f;
    const int  a2_abs   = base + 252 + t;
    const bool a2_colok = (t < 8) && (a2_abs < W);
    const float invCwA2 = a2_colok
        ? 1.0f / (float)(min(a2_abs + RADIUS, W - 1) - max(a2_abs - RADIUS, 0) + 1) : 0.f;
    const int   c_abs  = base + t;
    const float invCwO = 1.0f / (float)(min(c_abs + RADIUS, W - 1) - max(c_abs - RADIUS, 0) + 1);
    const int  lc1   = base + t - 8;
    const bool lc1ok = (lc1 >= 0) && (lc1 < W);
    const int  lc2   = base + 248 + t;
    const bool lc2ok = (t < 16) && (lc2 < W);

    // ---- rings (literal-index only) ----
    float hx[9], hy[9], hxy[9], hxx[9];   // h-sum history, oldest at [0]
    float aA[9], aB[9];                   // A,b h-sum history
#pragma unroll
    for (int i = 0; i < 9; ++i) { hx[i]=hy[i]=hxy[i]=hxx[i]=0.f; aA[i]=aB[i]=0.f; }
    // x-delay pair ring, depth 4 steps (named scalars)
    float q0a=0.f,q0b=0.f,q1a=0.f,q1b=0.f,q2a=0.f,q2b=0.f,q3a=0.f,q3b=0.f;
    float vx=0.f, vy=0.f, vxy=0.f, vxx=0.f;
    float v2x=0.f, v2y=0.f, v2xy=0.f, v2xx=0.f;
    float vA=0.f, vB=0.f;

    if (t < 72) ((float4*)tring)[t] = make_float4(0.f,0.f,0.f,0.f);

    // ---- prologue: xybuf[0] <- rows R0-8, R0-7 ; prefetch rows R0-6, R0-5 ----
    {
        int g0 = R0 - 8, g1 = R0 - 7;
        bool k0 = (g0 >= 0), k1 = (g1 >= 0);
        const float *x0 = xp + g0 * W, *y0 = yp + g0 * W;
        const float *x1 = xp + g1 * W, *y1 = yp + g1 * W;
        float a0 = (k0 && lc1ok) ? x0[lc1] : 0.f, b0 = (k0 && lc1ok) ? y0[lc1] : 0.f;
        float a1 = (k1 && lc1ok) ? x1[lc1] : 0.f, b1 = (k1 && lc1ok) ? y1[lc1] : 0.f;
        xybuf[0][t] = make_float4(a0, b0, a1, b1);
        if (t < 16) {
            float c0 = (k0 && lc2ok) ? x0[lc2] : 0.f, d0 = (k0 && lc2ok) ? y0[lc2] : 0.f;
            float c1 = (k1 && lc2ok) ? x1[lc2] : 0.f, d1 = (k1 && lc2ok) ? y1[lc2] : 0.f;
            xybuf[0][256 + t] = make_float4(c0, d0, c1, d1);
        }
    }
    float p0x, p0y, p0x2, p0y2, p1x, p1y, p1x2, p1y2;
    {
        int g0 = R0 - 6, g1 = R0 - 5;
        bool k0 = (g0 >= 0), k1 = (g1 >= 0);
        const float *x0 = xp + g0 * W, *y0 = yp + g0 * W;
        const float *x1 = xp + g1 * W, *y1 = yp + g1 * W;
        p0x  = (k0 && lc1ok) ? x0[lc1] : 0.f;  p0y  = (k0 && lc1ok) ? y0[lc1] : 0.f;
        p1x  = (k1 && lc1ok) ? x1[lc1] : 0.f;  p1y  = (k1 && lc1ok) ? y1[lc1] : 0.f;
        p0x2 = (k0 && lc2ok) ? x0[lc2] : 0.f;  p0y2 = (k0 && lc2ok) ? y0[lc2] : 0.f;
        p1x2 = (k1 && lc2ok) ? x1[lc2] : 0.f;  p1y2 = (k1 && lc2ok) ? y1[lc2] : 0.f;
    }
    __syncthreads();

    int sl0 = 0;   // (2*S) % 9, maintained incrementally (uniform SALU)

    for (int S = 0; S < NSTEP; ++S) {
        const int r0  = R0 - 16 + 2 * S;
        const int cur = S & 1, nxt = cur ^ 1;
        const int sl1 = (sl0 + 1 == 9) ? 0 : sl0 + 1;

        // delayed x at output rows (captured 4 steps ago)
        const float xq0 = q0a, xq1 = q0b;

        // -- publish rows r0+10, r0+11 --
        xybuf[nxt][t] = make_float4(p0x, p0y, p1x, p1y);
        if (t < 16) xybuf[nxt][256 + t] = make_float4(p0x2, p0y2, p1x2, p1y2);

        // -- prefetch rows r0+12, r0+13 --
        {
            int g0 = r0 + 12, g1 = r0 + 13;
            bool k0 = (g0 >= 0) && (g0 < H);
            bool k1 = (g1 >= 0) && (g1 < H);
            const float *x0 = xp + g0 * W, *y0 = yp + g0 * W;
            const float *x1 = xp + g1 * W, *y1 = yp + g1 * W;
            p0x  = (k0 && lc1ok) ? x0[lc1] : 0.f;  p0y  = (k0 && lc1ok) ? y0[lc1] : 0.f;
            p1x  = (k1 && lc1ok) ? x1[lc1] : 0.f;  p1y  = (k1 && lc1ok) ? y1[lc1] : 0.f;
            p0x2 = (k0 && lc2ok) ? x0[lc2] : 0.f;  p0y2 = (k0 && lc2ok) ? y0[lc2] : 0.f;
            p1x2 = (k1 && lc2ok) ? x1[lc2] : 0.f;  p1y2 = (k1 && lc2ok) ? y1[lc2] : 0.f;
        }

        // -- NH: 9 b128 taps -> h-sums for rows r0+8 (x0y0) and r0+9 (x1y1) --
        float nx0=0.f,ny0=0.f,nxy0=0.f,nxx0=0.f;
        float nx1=0.f,ny1=0.f,nxy1=0.f,nxx1=0.f;
        float4 tap;
#pragma unroll
        for (int d = 0; d < 9; ++d) {
            tap = xybuf[cur][t + d];
            nx0 += tap.x; ny0 += tap.y; nxy0 += tap.x * tap.y; nxx0 += tap.x * tap.x;
            nx1 += tap.z; ny1 += tap.w; nxy1 += tap.z * tap.w; nxx1 += tap.z * tap.z;
        }
        // last tap (d=8) is region col t+8 == c_abs: capture for the x-delay ring
        const float capa = tap.x, capb = tap.z;

        // -- vertical rings + A,b (row0 then row1), literal indices --
        vx  += nx0  - hx[0];
        vy  += ny0  - hy[0];
        vxy += nxy0 - hxy[0];
        vxx += nxx0 - hxx[0];
        float A0 = 0.f, B0 = 0.f;
        const int ra0 = r0 + 4;
        if (S >= 4 && a_colok && ra0 >= 0 && ra0 < H) {
            const float invCh = 1.0f /
                (float)(min(ra0 + RADIUS, H - 1) - max(ra0 - RADIUS, 0) + 1);
            float invN = invCh * invCwA;
            float mx = vx * invN, my = vy * invN;
            float cov = vxy * invN - mx * my;
            float vr  = vxx * invN - mx * mx;
            A0 = cov * __builtin_amdgcn_rcpf(vr + 0.1f);
            B0 = my - A0 * mx;
        }
        vx  += nx1  - hx[1];
        vy  += ny1  - hy[1];
        vxy += nxy1 - hxy[1];
        vxx += nxx1 - hxx[1];
        float A1 = 0.f, B1 = 0.f;
        const int ra1 = r0 + 5;
        if (S >= 4 && a_colok && ra1 >= 0 && ra1 < H) {
            const float invCh = 1.0f /
                (float)(min(ra1 + RADIUS, H - 1) - max(ra1 - RADIUS, 0) + 1);
            float invN = invCh * invCwA;
            float mx = vx * invN, my = vy * invN;
            float cov = vxy * invN - mx * my;
            float vr  = vxx * invN - mx * mx;
            A1 = cov * __builtin_amdgcn_rcpf(vr + 0.1f);
            B1 = my - A1 * mx;
        }
        abbuf[cur][t] = make_float4(A0, B0, A1, B1);
        // shift-by-2 (all literal indices)
        hx[0]=hx[2];   hx[1]=hx[3];   hx[2]=hx[4];   hx[3]=hx[5];
        hx[4]=hx[6];   hx[5]=hx[7];   hx[6]=hx[8];   hx[7]=nx0;   hx[8]=nx1;
        hy[0]=hy[2];   hy[1]=hy[3];   hy[2]=hy[4];   hy[3]=hy[5];
        hy[4]=hy[6];   hy[5]=hy[7];   hy[6]=hy[8];   hy[7]=ny0;   hy[8]=ny1;
        hxy[0]=hxy[2]; hxy[1]=hxy[3]; hxy[2]=hxy[4]; hxy[3]=hxy[5];
        hxy[4]=hxy[6]; hxy[5]=hxy[7]; hxy[6]=hxy[8]; hxy[7]=nxy0; hxy[8]=nxy1;
        hxx[0]=hxx[2]; hxx[1]=hxx[3]; hxx[2]=hxx[4]; hxx[3]=hxx[5];
        hxx[4]=hxx[6]; hxx[5]=hxx[7]; hxx[6]=hxx[8]; hxx[7]=nxx0; hxx[8]=nxx1;

        // -- extra A-cols (region 260..267), lanes t<8; history in LDS tring --
        if (t < 8) {
            float ex0=0.f,ey0=0.f,exy0=0.f,exx0=0.f;
            float ex1=0.f,ey1=0.f,exy1=0.f,exx1=0.f;
#pragma unroll
            for (int d = 0; d < 9; ++d) {
                float4 v = xybuf[cur][256 + t + d];
                ex0 += v.x; ey0 += v.y; exy0 += v.x * v.y; exx0 += v.x * v.x;
                ex1 += v.z; ey1 += v.w; exy1 += v.z * v.w; exx1 += v.z * v.z;
            }
            float4 o0 = tring[sl0][t];
            v2x += ex0 - o0.x; v2y += ey0 - o0.y; v2xy += exy0 - o0.z; v2xx += exx0 - o0.w;
            tring[sl0][t] = make_float4(ex0, ey0, exy0, exx0);
            float A20 = 0.f, B20 = 0.f;
            if (S >= 4 && a2_colok && ra0 >= 0 && ra0 < H) {
                const float invCh = 1.0f /
                    (float)(min(ra0 + RADIUS, H - 1) - max(ra0 - RADIUS, 0) + 1);
                float invN = invCh * invCwA2;
                float mx = v2x * invN, my = v2y * invN;
                float cov = v2xy * invN - mx * my;
                float vr  = v2xx * invN - mx * mx;
                A20 = cov * __builtin_amdgcn_rcpf(vr + 0.1f);
                B20 = my - A20 * mx;
            }
            float4 o1 = tring[sl1][t];
            v2x += ex1 - o1.x; v2y += ey1 - o1.y; v2xy += exy1 - o1.z; v2xx += exx1 - o1.w;
            tring[sl1][t] = make_float4(ex1, ey1, exy1, exx1);
            float A21 = 0.f, B21 = 0.f;
            if (S >= 4 && a2_colok && ra1 >= 0 && ra1 < H) {
                const float invCh = 1.0f /
                    (float)(min(ra1 + RADIUS, H - 1) - max(ra1 - RADIUS, 0) + 1);
                float invN = invCh * invCwA2;
                float mx = v2x * invN, my = v2y * invN;
                float cov = v2xy * invN - mx * my;
                float vr  = v2xx * invN - mx * mx;
                A21 = cov * __builtin_amdgcn_rcpf(vr + 0.1f);
                B21 = my - A21 * mx;
            }
            abbuf[cur][256 + t] = make_float4(A20, B20, A21, B21);
        }

        __syncthreads();   // single barrier per step

        // -- O: 9 b128 taps of A,b -> both output rows --
        if (S >= 4) {
            float hA0=0.f,hB0=0.f,hA1=0.f,hB1=0.f;
#pragma unroll
            for (int d = 0; d < 9; ++d) {
                float4 v = abbuf[cur][t + d];
                hA0 += v.x; hB0 += v.y; hA1 += v.z; hB1 += v.w;
            }
            vA += hA0 - aA[0];
            vB += hB0 - aB[0];
            if (S >= 8) {
                const float invCh = 1.0f /
                    (float)(min(r0 + RADIUS, H - 1) - max(r0 - RADIUS, 0) + 1);
                float invN = invCh * invCwO;
                op[r0 * W + c_abs] = (vA * invN) * xq0 + (vB * invN);
            }
            vA += hA1 - aA[1];
            vB += hB1 - aB[1];
            if (S >= 8) {
                const int r = r0 + 1;
                const float invCh = 1.0f /
                    (float)(min(r + RADIUS, H - 1) - max(r - RADIUS, 0) + 1);
                float invN = invCh * invCwO;
                op[r * W + c_abs] = (vA * invN) * xq1 + (vB * invN);
            }
            aA[0]=aA[2]; aA[1]=aA[3]; aA[2]=aA[4]; aA[3]=aA[5];
            aA[4]=aA[6]; aA[5]=aA[7]; aA[6]=aA[8]; aA[7]=hA0; aA[8]=hA1;
            aB[0]=aB[2]; aB[1]=aB[3]; aB[2]=aB[4]; aB[3]=aB[5];
            aB[4]=aB[6]; aB[5]=aB[7]; aB[6]=aB[8]; aB[7]=hB0; aB[8]=hB1;
        }

        // x-delay ring shift (depth 4)
        q0a=q1a; q0b=q1b; q1a=q2a; q1b=q2b; q2a=q3a; q2b=q3b;
        q3a=capa; q3b=capb;

        sl0 += 2; if (sl0 >= 9) sl0 -= 9;
    }
}

extern "C" void kernel_launch(void* const* d_in, const int* in_sizes, int n_in,
                              void* d_out, int out_size, void* d_ws, size_t ws_size,
                              hipStream_t stream) {
    const float* x = (const float*)d_in[0];
    const float* y = (const float*)d_in[1];
    float* out = (float*)d_out;

    dim3 grid(W / SW, H / ROWS, 24);   // 3 x 24 x 24 = 1728 blocks (~6.75/CU)
    dim3 block(256);
    hipLaunchKernelGGL(gf_stream5, grid, block, 0, stream, x, y, out);
}

// Round 8
// 123.892 us; speedup vs baseline: 2.4477x; 2.4477x over previous
//
#include <hip/hip_runtime.h>

#define H 768
#define W 768
#define SW 256        // output cols per strip
#define RW 272        // region width (SW + 16)
#define ABW 264       // A,b row width (SW + 8)
#define ROWS 48       // output rows per band
#define STEPS 64      // ROWS + 16 single-row steps
#define XR 11         // x-delay ring depth (11 needed for 1-barrier schedule)
#define RADIUS 4

// Single-row stream (R3's register envelope: the ONLY shape that compiled
// scratch-free) + double-buffered rows + ONE barrier per step.
// Every double-row variant spilled (WRITE_SIZE 112..669 MB of scratch).
__global__ __launch_bounds__(256, 4) void gf_stream6(
    const float* __restrict__ xg, const float* __restrict__ yg,
    float* __restrict__ outg)
{
    __shared__ float2 xybuf[2][RW];   // double-buffered x,y row      4352 B
    __shared__ float2 abbuf[2][ABW];  // double-buffered A,b row      4224 B
    __shared__ float  xring[XR][RW];  // x delay line for output     11968 B
    __shared__ float4 tring[9][8];    // extra-col h-ring (t<8 RMW)   1152 B

    const int t     = threadIdx.x;
    const int base  = blockIdx.x * SW;
    const int R0    = blockIdx.y * ROWS;
    const int plane = blockIdx.z;

    const float* xp = xg + (size_t)plane * (H * W);
    const float* yp = yg + (size_t)plane * (H * W);
    float*       op = outg + (size_t)plane * (H * W);

    // ---- per-thread column geometry (loop-invariant) ----
    const int  a_abs   = base + t - 4;                  // main A-col
    const bool a_colok = (a_abs >= 0) && (a_abs < W);
    const float invCwA = a_colok
        ? 1.0f / (float)(min(a_abs + RADIUS, W - 1) - max(a_abs - RADIUS, 0) + 1) : 0.f;
    const int  a2_abs   = base + 252 + t;               // extra A-col (t<8)
    const bool a2_colok = (t < 8) && (a2_abs < W);
    const float invCwA2 = a2_colok
        ? 1.0f / (float)(min(a2_abs + RADIUS, W - 1) - max(a2_abs - RADIUS, 0) + 1) : 0.f;
    const int   c_abs  = base + t;                      // output col
    const float invCwO = 1.0f / (float)(min(c_abs + RADIUS, W - 1) - max(c_abs - RADIUS, 0) + 1);
    const int  lc1   = base + t - 8;                    // load col (region col t)
    const bool lc1ok = (lc1 >= 0) && (lc1 < W);
    const int  lc2   = base + 248 + t;                  // load col (region col 256+t), t<16
    const bool lc2ok = (t < 16) && (lc2 < W);

    // ---- register rings (indexed by the 9-unroll variable u => static) ----
    float hx[9], hy[9], hxy[9], hxx[9];   // h-sum history (col a_abs)
    float aA[9], aB[9];                   // A,b h-sum history (col c_abs)
#pragma unroll
    for (int i = 0; i < 9; ++i) { hx[i]=hy[i]=hxy[i]=hxx[i]=0.f; aA[i]=aB[i]=0.f; }
    float vx=0.f, vy=0.f, vxy=0.f, vxx=0.f;       // vertical sums (col a_abs)
    float v2x=0.f, v2y=0.f, v2xy=0.f, v2xx=0.f;   // vertical sums (extra col)
    float vA=0.f, vB=0.f;                         // vertical sums of hA,hB

    if (t < 72) ((float4*)tring)[t] = make_float4(0.f,0.f,0.f,0.f);

    // ---- prologue: xybuf[0] <- row R0-8 ; prefetch row R0-7 into regs ----
    {
        int g = R0 - 8;
        bool k = (g >= 0);
        const float *xr_ = xp + g * W, *yr_ = yp + g * W;
        float a = (k && lc1ok) ? xr_[lc1] : 0.f;
        float b = (k && lc1ok) ? yr_[lc1] : 0.f;
        xybuf[0][t] = make_float2(a, b);
        if (t < 16) {
            float c = (k && lc2ok) ? xr_[lc2] : 0.f;
            float d = (k && lc2ok) ? yr_[lc2] : 0.f;
            xybuf[0][256 + t] = make_float2(c, d);
        }
    }
    float px_, py_, px2_, py2_;
    {
        int g = R0 - 7;
        bool k = (g >= 0);
        const float *xr_ = xp + g * W, *yr_ = yp + g * W;
        px_  = (k && lc1ok) ? xr_[lc1] : 0.f;  py_  = (k && lc1ok) ? yr_[lc1] : 0.f;
        px2_ = (k && lc2ok) ? xr_[lc2] : 0.f;  py2_ = (k && lc2ok) ? yr_[lc2] : 0.f;
    }
    __syncthreads();

    for (int S0 = 0; S0 < STEPS; S0 += 9) {
#pragma unroll
        for (int u = 0; u < 9; ++u) {
            const int S = S0 + u;
            if (S < STEPS) {                     // uniform guard
                const int r   = R0 - 16 + S;     // output row this step
                const int cur = S & 1, nxt = cur ^ 1;
                // xring slots (uniform; +offsets keep args nonnegative)
                const int slw = (R0 + S + 15) % XR;   // row r+9 goes here
                const int slr = (R0 + S + 6)  % XR;   // row r read here

                // -- publish row r+9 (prefetched last step) into the other buffer --
                xybuf[nxt][t] = make_float2(px_, py_);
                xring[slw][t] = px_;
                if (t < 16) {
                    xybuf[nxt][256 + t] = make_float2(px2_, py2_);
                    xring[slw][256 + t] = px2_;
                }
                // -- prefetch row r+10 --
                {
                    int g = r + 10;
                    bool k = (g >= 0) && (g < H);
                    const float *xr_ = xp + g * W, *yr_ = yp + g * W;
                    px_  = (k && lc1ok) ? xr_[lc1] : 0.f;  py_  = (k && lc1ok) ? yr_[lc1] : 0.f;
                    px2_ = (k && lc2ok) ? xr_[lc2] : 0.f;  py2_ = (k && lc2ok) ? yr_[lc2] : 0.f;
                }

                // -- NH: 9-tap horizontal sums of row r+8 (published last step) --
                float nx=0.f, ny=0.f, nxy=0.f, nxx=0.f;
#pragma unroll
                for (int d = 0; d < 9; ++d) {
                    float2 v = xybuf[cur][t + d];
                    nx += v.x; ny += v.y; nxy += v.x * v.y; nxx += v.x * v.x;
                }
                vx  += nx  - hx[u];  hx[u]  = nx;
                vy  += ny  - hy[u];  hy[u]  = ny;
                vxy += nxy - hxy[u]; hxy[u] = nxy;
                vxx += nxx - hxx[u]; hxx[u] = nxx;

                // -- A,b at image row ra = r+4 (valid from S=8) --
                const int ra = r + 4;
                if (S >= 8) {
                    float A0 = 0.f, B0 = 0.f;
                    if (a_colok && ra >= 0 && ra < H) {
                        const float invCh = 1.0f /
                            (float)(min(ra + RADIUS, H - 1) - max(ra - RADIUS, 0) + 1);
                        float invN = invCh * invCwA;
                        float mx = vx * invN, my = vy * invN;
                        float cov = vxy * invN - mx * my;
                        float vr  = vxx * invN - mx * mx;
                        A0 = cov * __builtin_amdgcn_rcpf(vr + 0.1f);
                        B0 = my - A0 * mx;
                    }
                    abbuf[cur][t] = make_float2(A0, B0);
                }
                // -- extra A-cols (region 260..267), lanes t<8; LDS history ring --
                if (t < 8) {
                    float ex=0.f, ey=0.f, exy=0.f, exx=0.f;
#pragma unroll
                    for (int d = 0; d < 9; ++d) {
                        float2 v = xybuf[cur][256 + t + d];
                        ex += v.x; ey += v.y; exy += v.x * v.y; exx += v.x * v.x;
                    }
                    float4 o = tring[u][t];
                    v2x += ex - o.x; v2y += ey - o.y; v2xy += exy - o.z; v2xx += exx - o.w;
                    tring[u][t] = make_float4(ex, ey, exy, exx);
                    if (S >= 8) {
                        float A2 = 0.f, B2 = 0.f;
                        if (a2_colok && ra >= 0 && ra < H) {
                            const float invCh = 1.0f /
                                (float)(min(ra + RADIUS, H - 1) - max(ra - RADIUS, 0) + 1);
                            float invN = invCh * invCwA2;
                            float mx = v2x * invN, my = v2y * invN;
                            float cov = v2xy * invN - mx * my;
                            float vr  = v2xx * invN - mx * mx;
                            A2 = cov * __builtin_amdgcn_rcpf(vr + 0.1f);
                            B2 = my - A2 * mx;
                        }
                        abbuf[cur][256 + t] = make_float2(A2, B2);
                    }
                }

                __syncthreads();   // the ONLY barrier per step

                // -- O: 9-tap horizontal of A,b + vertical ring + store row r --
                if (S >= 8) {
                    float hA=0.f, hB=0.f;
#pragma unroll
                    for (int d = 0; d < 9; ++d) {
                        float2 v = abbuf[cur][t + d];
                        hA += v.x; hB += v.y;
                    }
                    vA += hA - aA[u]; aA[u] = hA;
                    vB += hB - aB[u]; aB[u] = hB;
                    if (S >= 16) {
                        float xo = xring[slr][t + 8];   // x(r, c_abs)
                        const float invCh = 1.0f /
                            (float)(min(r + RADIUS, H - 1) - max(r - RADIUS, 0) + 1);
                        float invN = invCh * invCwO;
                        op[r * W + c_abs] = (vA * invN) * xo + (vB * invN);
                    }
                }
            }
        }
    }
}

extern "C" void kernel_launch(void* const* d_in, const int* in_sizes, int n_in,
                              void* d_out, int out_size, void* d_ws, size_t ws_size,
                              hipStream_t stream) {
    const float* x = (const float*)d_in[0];
    const float* y = (const float*)d_in[1];
    float* out = (float*)d_out;

    dim3 grid(W / SW, H / ROWS, 24);   // 3 x 16 x 24 = 1152 blocks (~4.5/CU)
    dim3 block(256);
    hipLaunchKernelGGL(gf_stream6, grid, block, 0, stream, x, y, out);
}